// Round 1
// 190.617 us; speedup vs baseline: 1.0589x; 1.0589x over previous
//
#include <hip/hip_runtime.h>

// SetEq4to4: out[n,so,i,j,k,l] = sum over 69 basis ops (A,B) + bias.
// n=2, d=8, so=8, N=32, basis=69.
//
// Pipeline (atomic-free):
//   KR k_red3  (1024 blk x 512 thr, one x-pass per red3 family):
//        blocks [0,512):  (nd,i) -> r012[i,j,k], r013[i,j,l], r023[i,k,l]
//                          (r023 = free register accumulation over the j loop;
//                           cross-wave combines deferred to ONE sync epilogue)
//        blocks [512,1024): (nd,j) -> r123[j,k,l]  (i-parity split, LDS combine)
//   K3 k_red21: red2 (6) + red1 (4) derived from r012/r013/r023
//   K4 k_mix21: T2f/T1f = channel-mixed red2/red1
//   K5 k_mix3:  U3[b] = channel-mixed red3 + folded T2f/T1f/bias
//   K6 k_final: out = sum_d c68*x + U012 + U013 + U023 + U123

constexpr size_t R3SZ  = 524288;   // per-a: 16 nd * 32768
constexpr size_t R2SZ  = 16384;    // per-b2: 16 nd * 1024
constexpr size_t R1SZ  = 512;      // per-b1: 16 nd * 32
constexpr size_t R3OFF = 0;
constexpr size_t R2OFF = R3OFF + 4 * R3SZ;   // red2: b2 0..5 = (01)(02)(03)(12)(13)(23)
constexpr size_t R1OFF = R2OFF + 6 * R2SZ;   // red1: b1 0..3 = (0)(1)(2)(3)
constexpr size_t T2OFF = R1OFF + 4 * R1SZ;
constexpr size_t T1OFF = T2OFF + 6 * R2SZ;
constexpr size_t U3OFF = T1OFF + 4 * R1SZ;
// total ws floats: U3OFF + 4*R3SZ = 4395008  (~17.6 MiB)

// ---------------- KR: all four rank-3 reductions, x read twice total ----------------
__global__ __launch_bounds__(512) void k_red3(const float* __restrict__ x,
                                              float* __restrict__ ws) {
    __shared__ float4 cp[32][4][8];   // [j][k-octet][l4] col partials (16 KiB)
    __shared__ float  b012[1024];     // [j][k] row sums (4 KiB)
    __shared__ float4 a2[256];        // half-1 accumulator park (4 KiB)
    const int bid  = blockIdx.x;
    const int t    = threadIdx.x;
    const int half = t >> 8;          // parity of the loop axis handled by this half
    const int tt   = t & 255;
    const int k    = tt >> 3;         // k index owned by this thread
    const int l4   = tt & 7;          // l-quad owned by this thread

    if (bid < 512) {
        // -------- plane blocks: fixed (nd, i), loop over j --------
        const int i    = bid & 31;
        const int nd   = bid >> 5;
        const int w4   = (t >> 6) & 3;   // which k-octet this wave covers
        const int lane = t & 63;
        const float* xp = x + ((size_t)nd << 20) + ((size_t)i << 15) + k * 32 + l4 * 4;
        float4 acc = {0.f, 0.f, 0.f, 0.f};           // r023[i,k,l] accumulator
        #pragma unroll
        for (int it = 0; it < 16; ++it) {
            const int j = it * 2 + half;
            float4 v = *(const float4*)(xp + j * 1024);
            acc.x += v.x; acc.y += v.y; acc.z += v.z; acc.w += v.w;
            // r012[i,j,k] = sum over l: hsum + butterfly over lane bits 0..2
            float h = v.x + v.y + v.z + v.w;
            h += __shfl_xor(h, 1); h += __shfl_xor(h, 2); h += __shfl_xor(h, 4);
            if (l4 == 0) b012[j * 32 + k] = h;
            // col partials over this wave's 8 k's: butterfly over lane bits 3..5
            v.x += __shfl_xor(v.x, 8);  v.y += __shfl_xor(v.y, 8);
            v.z += __shfl_xor(v.z, 8);  v.w += __shfl_xor(v.w, 8);
            v.x += __shfl_xor(v.x, 16); v.y += __shfl_xor(v.y, 16);
            v.z += __shfl_xor(v.z, 16); v.w += __shfl_xor(v.w, 16);
            v.x += __shfl_xor(v.x, 32); v.y += __shfl_xor(v.y, 32);
            v.z += __shfl_xor(v.z, 32); v.w += __shfl_xor(v.w, 32);
            if (lane < 8) cp[j][w4][lane] = v;
        }
        if (half == 1) a2[tt] = acc;                 // park for r023 combine
        __syncthreads();                             // the ONLY sync
        const size_t base = ((size_t)nd << 15) + ((size_t)i << 10);
        // r012 write: [i][j*32+k], 2 floats/thread, fully coalesced
        *(float2*)(ws + R3OFF + base + 2 * t) = *(const float2*)(b012 + 2 * t);
        if (half == 0) {
            // r013[i,j,l]: combine the 4 k-octet partials
            const int j = tt >> 3, lj = tt & 7;
            float4 s0 = cp[j][0][lj], s1 = cp[j][1][lj];
            float4 s2 = cp[j][2][lj], s3 = cp[j][3][lj];
            float4 s;
            s.x = s0.x + s1.x + s2.x + s3.x;
            s.y = s0.y + s1.y + s2.y + s3.y;
            s.z = s0.z + s1.z + s2.z + s3.z;
            s.w = s0.w + s1.w + s2.w + s3.w;
            *(float4*)(ws + R3OFF + R3SZ + base + j * 32 + lj * 4) = s;
            // r023[i,k,l]: merge the two j-parity halves
            float4 b = a2[tt];
            acc.x += b.x; acc.y += b.y; acc.z += b.z; acc.w += b.w;
            *(float4*)(ws + R3OFF + 2 * R3SZ + base + k * 32 + l4 * 4) = acc;
        }
    } else {
        // -------- col blocks: fixed (nd, j), loop over i --------
        const int bb = bid - 512;
        const int j  = bb & 31;
        const int nd = bb >> 5;
        const float* xp = x + ((size_t)nd << 20) + (size_t)j * 1024 + (size_t)tt * 4;
        float4 acc = {0.f, 0.f, 0.f, 0.f};
        #pragma unroll
        for (int it = 0; it < 16; ++it) {
            const int i = it * 2 + half;
            float4 v = *(const float4*)(xp + ((size_t)i << 15));
            acc.x += v.x; acc.y += v.y; acc.z += v.z; acc.w += v.w;
        }
        if (half == 1) a2[tt] = acc;
        __syncthreads();
        if (half == 0) {
            float4 b = a2[tt];
            acc.x += b.x; acc.y += b.y; acc.z += b.z; acc.w += b.w;
            *(float4*)(ws + R3OFF + 3 * R3SZ + ((size_t)nd << 15)
                       + ((size_t)j << 10) + tt * 4) = acc;
        }
    }
}

// ---------------- K3: red2 (6) + red1 (4) from red3 ----------------
__global__ __launch_bounds__(256) void k_red21(float* __restrict__ ws) {
    const int gid = blockIdx.x * 256 + threadIdx.x;   // grid 392*256 = 100352
    if (gid < 98304) {
        const int b2 = gid >> 14;
        const int r  = gid & 16383;
        const int nd = r >> 10;
        const int p = (r >> 5) & 31, q = r & 31;
        const float* r012 = ws + R3OFF + ((size_t)nd << 15);
        const float* r013 = r012 + R3SZ;
        const float* r023 = r012 + 2 * R3SZ;
        float s = 0.f;
        switch (b2) {
            case 0: { const float* s0 = r012 + p * 1024 + q * 32;
                      for (int m = 0; m < 32; ++m) s += s0[m]; } break;
            case 1: { const float* s0 = r012 + p * 1024 + q;
                      for (int m = 0; m < 32; ++m) s += s0[m * 32]; } break;
            case 2: { const float* s0 = r013 + p * 1024 + q;
                      for (int m = 0; m < 32; ++m) s += s0[m * 32]; } break;
            case 3: { const float* s0 = r012 + p * 32 + q;
                      for (int m = 0; m < 32; ++m) s += s0[m * 1024]; } break;
            case 4: { const float* s0 = r013 + p * 32 + q;
                      for (int m = 0; m < 32; ++m) s += s0[m * 1024]; } break;
            default:{ const float* s0 = r023 + p * 32 + q;
                      for (int m = 0; m < 32; ++m) s += s0[m * 1024]; } break;
        }
        ws[R2OFF + (size_t)b2 * R2SZ + (size_t)nd * 1024 + p * 32 + q] = s;
    } else if (gid < 100352) {
        const int e  = gid - 98304;
        const int b1 = e >> 9;
        const int r  = e & 511;
        const int nd = r >> 5, p = r & 31;
        const float* r012 = ws + R3OFF + ((size_t)nd << 15);
        const float* r013 = r012 + R3SZ;
        float s = 0.f;
        if (b1 == 0)      { const float* s0 = r012 + p * 1024;
                            for (int m = 0; m < 1024; ++m) s += s0[m]; }
        else if (b1 == 1) { const float* s0 = r012 + p * 32;
                            for (int a = 0; a < 32; ++a) for (int m = 0; m < 32; ++m)
                                s += s0[a * 1024 + m]; }
        else if (b1 == 2) { const float* s0 = r012 + p;
                            for (int a = 0; a < 32; ++a) for (int m = 0; m < 32; ++m)
                                s += s0[a * 1024 + m * 32]; }
        else              { const float* s0 = r013 + p;
                            for (int a = 0; a < 32; ++a) for (int m = 0; m < 32; ++m)
                                s += s0[a * 1024 + m * 32]; }
        ws[R1OFF + (size_t)b1 * R1SZ + (size_t)nd * 32 + p] = s;
    }
}

// ---------------- K4: T2f/T1f = channel-mixed red2/red1 ----------------
__global__ __launch_bounds__(256) void k_mix21(const float* __restrict__ coefs,
                                               float* __restrict__ ws) {
    __shared__ float cs[4416];
    for (int idx = threadIdx.x; idx < 4416; idx += 256) cs[idx] = coefs[idx];
    __syncthreads();
    const int gid = blockIdx.x * 256 + threadIdx.x;
    if (gid < 98304) {
        const int b2 = gid >> 14;
        const int r  = gid & 16383;
        const int n  = r >> 13;
        const int so = (r >> 10) & 7;
        const int pq = r & 1023;
        float s = 0.f;
        #pragma unroll
        for (int a2 = 0; a2 < 6; ++a2) {
            const float* src = ws + R2OFF + (size_t)a2 * R2SZ + (size_t)(n * 8) * 1024 + pq;
            #pragma unroll
            for (int d = 0; d < 8; ++d)
                s += cs[(d * 8 + so) * 69 + 16 + a2 * 6 + b2] * src[d * 1024];
        }
        ws[T2OFF + (size_t)b2 * R2SZ + (size_t)(n * 8 + so) * 1024 + pq] = s;
    } else if (gid < 100352) {
        const int e  = gid - 98304;
        const int b1 = e >> 9;
        const int r  = e & 511;
        const int n  = r >> 8;
        const int so = (r >> 5) & 7;
        const int p  = r & 31;
        float s = 0.f;
        #pragma unroll
        for (int a1 = 0; a1 < 4; ++a1) {
            const float* src = ws + R1OFF + (size_t)a1 * R1SZ + (size_t)(n * 8) * 32 + p;
            #pragma unroll
            for (int d = 0; d < 8; ++d)
                s += cs[(d * 8 + so) * 69 + a1 * 4 + b1] * src[d * 32];
        }
        ws[T1OFF + (size_t)b1 * R1SZ + (size_t)(n * 8 + so) * 32 + p] = s;
    }
}

// ---------------- K5: U3[b] = mixed red3 + folded T2f/T1f/bias ----------------
__global__ __launch_bounds__(256) void k_mix3(const float* __restrict__ coefs,
                                              const float* __restrict__ bias,
                                              float* __restrict__ ws) {
    __shared__ float cs[4416];
    for (int idx = threadIdx.x; idx < 4416; idx += 256) cs[idx] = coefs[idx];
    __syncthreads();
    const int blk = blockIdx.x;           // 512 = n(1) | soh(1) | cb(7)
    const int cb  = blk & 127;
    const int soh = (blk >> 7) & 1;
    const int n   = blk >> 8;
    const int c   = cb * 256 + threadIdx.x;
    const int p1 = c >> 10, p2 = (c >> 5) & 31, p3 = c & 31;
    float v[4][8];
    #pragma unroll
    for (int a = 0; a < 4; ++a)
        #pragma unroll
        for (int d = 0; d < 8; ++d)
            v[a][d] = ws[R3OFF + (size_t)a * R3SZ + (size_t)(n * 8 + d) * 32768 + c];
    const float* T2 = ws + T2OFF;
    const float* T1 = ws + T1OFF;
    #pragma unroll
    for (int b = 0; b < 4; ++b) {
        #pragma unroll
        for (int so2 = 0; so2 < 4; ++so2) {
            const int so = soh * 4 + so2;
            float s = 0.f;
            #pragma unroll
            for (int a = 0; a < 4; ++a)
                #pragma unroll
                for (int d = 0; d < 8; ++d)
                    s += cs[(d * 8 + so) * 69 + 52 + a * 4 + b] * v[a][d];
            const size_t nso = (size_t)(n * 8 + so);
            if (b == 0) {
                s += T2[0 * R2SZ + nso * 1024 + p1 * 32 + p2];
                s += T2[1 * R2SZ + nso * 1024 + p1 * 32 + p3];
                s += T2[3 * R2SZ + nso * 1024 + p2 * 32 + p3];
                s += T1[0 * R1SZ + nso * 32 + p1];
                s += T1[1 * R1SZ + nso * 32 + p2];
                s += T1[2 * R1SZ + nso * 32 + p3];
                s += bias[so];
            } else if (b == 1) {
                s += T2[2 * R2SZ + nso * 1024 + p1 * 32 + p3];
                s += T2[4 * R2SZ + nso * 1024 + p2 * 32 + p3];
                s += T1[3 * R1SZ + nso * 32 + p3];
            } else if (b == 2) {
                s += T2[5 * R2SZ + nso * 1024 + p2 * 32 + p3];
            }
            ws[U3OFF + (size_t)b * R3SZ + nso * 32768 + c] = s;
        }
    }
}

// ---------------- K6: final broadcast-add + s=4 channel mix ----------------
__global__ __launch_bounds__(256) void k_final(const float* __restrict__ x,
                                               const float* __restrict__ coefs,
                                               const float* __restrict__ ws,
                                               float* __restrict__ out) {
    __shared__ float c68[64];
    if (threadIdx.x < 64) c68[threadIdx.x] = coefs[threadIdx.x * 69 + 68];
    __syncthreads();
    const int b = blockIdx.x;           // (n*32+i)*32 + j
    const int j = b & 31;
    const int i = (b >> 5) & 31;
    const int n = b >> 10;
    const int t = threadIdx.x;
    const int k = t >> 3, lq = t & 7;

    float4 xv[8];
    const float* xb = x + ((size_t)n << 23) + ((size_t)i << 15) + j * 1024 + k * 32 + lq * 4;
    #pragma unroll
    for (int d = 0; d < 8; ++d) xv[d] = *(const float4*)(xb + ((size_t)d << 20));

    const float* U = ws + U3OFF;
    const size_t c012 = (size_t)i * 1024 + j * 32 + k;
    const size_t c013 = (size_t)i * 1024 + j * 32 + lq * 4;
    const size_t c023 = (size_t)i * 1024 + k * 32 + lq * 4;
    const size_t c123 = (size_t)j * 1024 + k * 32 + lq * 4;

    #pragma unroll
    for (int so = 0; so < 8; ++so) {
        const size_t nso = (size_t)(n * 8 + so) << 15;
        const float  u0 = U[0 * R3SZ + nso + c012];
        const float4 u1 = *(const float4*)(U + 1 * R3SZ + nso + c013);
        const float4 u2 = *(const float4*)(U + 2 * R3SZ + nso + c023);
        const float4 u3 = *(const float4*)(U + 3 * R3SZ + nso + c123);
        float4 acc;
        acc.x = u0 + u1.x + u2.x + u3.x;
        acc.y = u0 + u1.y + u2.y + u3.y;
        acc.z = u0 + u1.z + u2.z + u3.z;
        acc.w = u0 + u1.w + u2.w + u3.w;
        #pragma unroll
        for (int d = 0; d < 8; ++d) {
            const float w = c68[d * 8 + so];
            acc.x += w * xv[d].x; acc.y += w * xv[d].y;
            acc.z += w * xv[d].z; acc.w += w * xv[d].w;
        }
        *(float4*)(out + ((size_t)(n * 8 + so) << 20) + ((size_t)i << 15)
                   + j * 1024 + k * 32 + lq * 4) = acc;
    }
}

extern "C" void kernel_launch(void* const* d_in, const int* in_sizes, int n_in,
                              void* d_out, int out_size, void* d_ws, size_t ws_size,
                              hipStream_t stream) {
    const float* x     = (const float*)d_in[0];
    const float* coefs = (const float*)d_in[1];
    const float* bias  = (const float*)d_in[2];
    float* out = (float*)d_out;
    float* ws  = (float*)d_ws;

    hipLaunchKernelGGL(k_red3, dim3(1024), dim3(512), 0, stream, x, ws);
    hipLaunchKernelGGL(k_red21, dim3(392),  dim3(256), 0, stream, ws);
    hipLaunchKernelGGL(k_mix21, dim3(392),  dim3(256), 0, stream, coefs, ws);
    hipLaunchKernelGGL(k_mix3,  dim3(512),  dim3(256), 0, stream, coefs, bias, ws);
    hipLaunchKernelGGL(k_final, dim3(2048), dim3(256), 0, stream, x, coefs, ws, out);
}

// Round 3
// 171.248 us; speedup vs baseline: 1.1786x; 1.1131x over previous
//
#include <hip/hip_runtime.h>

// SetEq4to4: out[n,so,i,j,k,l] = sum over 69 basis ops (A,B) + bias.
// n=2, d=8, so=8, N=32, basis=69.
//
// Pipeline (4 regular launches, no cooperative / no grid sync):
//   KR k_red3 (1024 blk x 512 thr): x -> r012,r013,r023 (plane blocks, one x pass)
//              and r123 (col blocks, second x pass). Epilogues ALSO emit
//              red2 pairs (01)(02)(03) [plane, from LDS] and (12)(13) [col,
//              from shuffles] -- only red2_(23) is cross-block.
//   KT k_mixT (66 blk x 256 thr): blocks 0..63 recompute red2_23 block-locally
//              from r023 (32-sum) and emit T2f (channel-mixed red2).
//              blocks 64..65 derive all red1 from red2 rows (32-sums) and emit T1f.
//   K5 k_mix3 (1024 blk x 256 thr): U3[b] = mixed red3 + folded T2f/T1f/bias.
//   K6 k_final: out = sum_d c68*x + U012 + U013 + U023 + U123

constexpr size_t R3SZ  = 524288;   // per-a: 16 nd * 32768
constexpr size_t R2SZ  = 16384;    // per-b2: 16 nd * 1024
constexpr size_t R1SZ  = 512;      // per-b1: 16 nd * 32  (region now unused)
constexpr size_t R3OFF = 0;
constexpr size_t R2OFF = R3OFF + 4 * R3SZ;   // red2: b2 0..5 = (01)(02)(03)(12)(13)(23)
constexpr size_t R1OFF = R2OFF + 6 * R2SZ;
constexpr size_t T2OFF = R1OFF + 4 * R1SZ;
constexpr size_t T1OFF = T2OFF + 6 * R2SZ;
constexpr size_t U3OFF = T1OFF + 4 * R1SZ;
// total ws floats: U3OFF + 4*R3SZ = 4395008  (~17.6 MiB)

// ---------------- KR: rank-3 reductions + most of red2 ----------------
__global__ __launch_bounds__(512) void k_red3(const float* __restrict__ x,
                                              float* __restrict__ ws) {
    __shared__ float4 cp[32][4][8];   // [j][k-octet][l4] col partials (16 KiB)
    __shared__ float  b012[1024];     // [j][k] row sums (4 KiB)
    __shared__ float4 a2[256];        // park buffer (4 KiB)
    const int bid  = blockIdx.x;
    const int t    = threadIdx.x;
    const int half = t >> 8;          // parity of the loop axis handled by this half
    const int tt   = t & 255;
    const int k    = tt >> 3;         // k index owned by this thread
    const int l4   = tt & 7;          // l-quad owned by this thread

    if (bid < 512) {
        // -------- plane blocks: fixed (nd, i), loop over j --------
        const int i    = bid & 31;
        const int nd   = bid >> 5;
        const int w4   = (t >> 6) & 3;   // which k-octet this wave covers
        const int lane = t & 63;
        const float* xp = x + ((size_t)nd << 20) + ((size_t)i << 15) + k * 32 + l4 * 4;
        float4 acc = {0.f, 0.f, 0.f, 0.f};           // r023[i,k,l] accumulator
        #pragma unroll
        for (int it = 0; it < 16; ++it) {
            const int j = it * 2 + half;
            float4 v = *(const float4*)(xp + j * 1024);
            acc.x += v.x; acc.y += v.y; acc.z += v.z; acc.w += v.w;
            // r012[i,j,k] = sum over l: hsum + butterfly over lane bits 0..2
            float h = v.x + v.y + v.z + v.w;
            h += __shfl_xor(h, 1); h += __shfl_xor(h, 2); h += __shfl_xor(h, 4);
            if (l4 == 0) b012[j * 32 + k] = h;
            // col partials over this wave's 8 k's: butterfly over lane bits 3..5
            v.x += __shfl_xor(v.x, 8);  v.y += __shfl_xor(v.y, 8);
            v.z += __shfl_xor(v.z, 8);  v.w += __shfl_xor(v.w, 8);
            v.x += __shfl_xor(v.x, 16); v.y += __shfl_xor(v.y, 16);
            v.z += __shfl_xor(v.z, 16); v.w += __shfl_xor(v.w, 16);
            v.x += __shfl_xor(v.x, 32); v.y += __shfl_xor(v.y, 32);
            v.z += __shfl_xor(v.z, 32); v.w += __shfl_xor(v.w, 32);
            if (lane < 8) cp[j][w4][lane] = v;
        }
        if (half == 1) a2[tt] = acc;                 // park for r023 combine
        __syncthreads();
        const size_t base = ((size_t)nd << 15) + ((size_t)i << 10);
        // r012 write: [i][j*32+k], 2 floats/thread, fully coalesced
        *(float2*)(ws + R3OFF + base + 2 * t) = *(const float2*)(b012 + 2 * t);
        if (half == 0) {
            // r013[i,j,l]: combine the 4 k-octet partials
            const int j = tt >> 3, lj = tt & 7;
            float4 s0 = cp[j][0][lj], s1 = cp[j][1][lj];
            float4 s2 = cp[j][2][lj], s3 = cp[j][3][lj];
            float4 s;
            s.x = s0.x + s1.x + s2.x + s3.x;
            s.y = s0.y + s1.y + s2.y + s3.y;
            s.z = s0.z + s1.z + s2.z + s3.z;
            s.w = s0.w + s1.w + s2.w + s3.w;
            *(float4*)(ws + R3OFF + R3SZ + base + j * 32 + lj * 4) = s;
            // r023[i,k,l]: merge the two j-parity halves
            float4 b = a2[tt];
            a2[tt] = s;                              // repurpose: a2 (as float[1024]) = r013[j][l]
            acc.x += b.x; acc.y += b.y; acc.z += b.z; acc.w += b.w;
            *(float4*)(ws + R3OFF + 2 * R3SZ + base + k * 32 + l4 * 4) = acc;
        }
        __syncthreads();
        // epilogue 2: red2 (01)(02)(03) for this i
        const size_t r2b = (size_t)nd * 1024 + (size_t)i * 32;
        if (t < 32) {
            // red2_01[i][j=t] = sum_k b012[t*32+k]  (skewed k to avoid bank conflicts)
            float s = 0.f;
            #pragma unroll
            for (int kk = 0; kk < 32; ++kk) s += b012[t * 32 + ((kk + t) & 31)];
            ws[R2OFF + 0 * R2SZ + r2b + t] = s;
        } else if (t < 64) {
            // red2_02[i][k] = sum_j b012[j*32+k]  (bank = k, conflict-free)
            const int kc = t - 32;
            float s = 0.f;
            #pragma unroll
            for (int j = 0; j < 32; ++j) s += b012[j * 32 + kc];
            ws[R2OFF + 1 * R2SZ + r2b + kc] = s;
        } else if (t < 96) {
            // red2_03[i][l] = sum_j r013[i][j][l]  (a2 flat view = [j][l], bank = l)
            const int l = t - 64;
            const float* af = (const float*)a2;
            float s = 0.f;
            #pragma unroll
            for (int j = 0; j < 32; ++j) s += af[j * 32 + l];
            ws[R2OFF + 2 * R2SZ + r2b + l] = s;
        }
    } else {
        // -------- col blocks: fixed (nd, j), loop over i --------
        const int bb = bid - 512;
        const int j  = bb & 31;
        const int nd = bb >> 5;
        const float* xp = x + ((size_t)nd << 20) + (size_t)j * 1024 + (size_t)tt * 4;
        float4 acc = {0.f, 0.f, 0.f, 0.f};
        #pragma unroll
        for (int it = 0; it < 16; ++it) {
            const int i = it * 2 + half;
            float4 v = *(const float4*)(xp + ((size_t)i << 15));
            acc.x += v.x; acc.y += v.y; acc.z += v.z; acc.w += v.w;
        }
        if (half == 1) a2[tt] = acc;
        __syncthreads();
        const size_t r2b = (size_t)nd * 1024 + (size_t)j * 32;
        if (half == 0) {
            float4 b = a2[tt];
            acc.x += b.x; acc.y += b.y; acc.z += b.z; acc.w += b.w;
            *(float4*)(ws + R3OFF + 3 * R3SZ + ((size_t)nd << 15)
                       + ((size_t)j << 10) + tt * 4) = acc;   // r123[j][k][l]
            // red2_12[j][k] = sum_l r123: hsum + butterfly over lane bits 0..2
            float h = acc.x + acc.y + acc.z + acc.w;
            h += __shfl_xor(h, 1); h += __shfl_xor(h, 2); h += __shfl_xor(h, 4);
            if ((t & 7) == 0) ws[R2OFF + 3 * R2SZ + r2b + k] = h;
            // red2_13[j][l] = sum_k r123: butterfly lane bits 3..5, then cross-wave
            float4 c2 = acc;
            c2.x += __shfl_xor(c2.x, 8);  c2.y += __shfl_xor(c2.y, 8);
            c2.z += __shfl_xor(c2.z, 8);  c2.w += __shfl_xor(c2.w, 8);
            c2.x += __shfl_xor(c2.x, 16); c2.y += __shfl_xor(c2.y, 16);
            c2.z += __shfl_xor(c2.z, 16); c2.w += __shfl_xor(c2.w, 16);
            c2.x += __shfl_xor(c2.x, 32); c2.y += __shfl_xor(c2.y, 32);
            c2.z += __shfl_xor(c2.z, 32); c2.w += __shfl_xor(c2.w, 32);
            if ((t & 63) < 8) cp[0][t >> 6][t & 63] = c2;
        }
        __syncthreads();
        if (t < 8) {
            float4 s0 = cp[0][0][t], s1 = cp[0][1][t];
            float4 s2 = cp[0][2][t], s3 = cp[0][3][t];
            float4 s;
            s.x = s0.x + s1.x + s2.x + s3.x;
            s.y = s0.y + s1.y + s2.y + s3.y;
            s.z = s0.z + s1.z + s2.z + s3.z;
            s.w = s0.w + s1.w + s2.w + s3.w;
            *(float4*)(ws + R2OFF + 4 * R2SZ + r2b + t * 4) = s;
        }
    }
}

// ---------------- KT: red2_23 (local) + T2f, and red1-from-red2 + T1f ----------------
__global__ __launch_bounds__(256) void k_mixT(const float* __restrict__ coefs,
                                              float* __restrict__ ws) {
    __shared__ float cs[4416];
    __shared__ float s23[256];    // [d][pql]  (T2 blocks)
    __shared__ float r1[1024];    // [a1][d][p] (T1 blocks)
    const int tt = threadIdx.x;
    for (int idx = tt; idx < 4416; idx += 256) cs[idx] = coefs[idx];
    const int b = blockIdx.x;
    if (b < 64) {
        // ---- T2f for (n, pq chunk of 32) ----
        const int n  = b >> 5;
        const int ch = b & 31;
        // phase A: red2_23[d][pql] = sum_i r023[(n8+d)][i][ch*32+pql]
        {
            const int d  = tt >> 5, q0 = tt & 31;
            const float* r023p = ws + R3OFF + 2 * R3SZ
                                 + ((size_t)(n * 8 + d) << 15) + ch * 32 + q0;
            float s = 0.f;
            #pragma unroll
            for (int i = 0; i < 32; ++i) s += r023p[i * 1024];
            s23[d * 32 + q0] = s;
        }
        __syncthreads();
        // phase B: T2f[b2][n,so,pq] = sum_{a2,d} cs[(d8+so)*69+16+a2*6+b2]*red2[a2][n8+d][pq]
        const int so = tt >> 5, pql = tt & 31;
        const int pq = ch * 32 + pql;
        float r2v[5][8];
        #pragma unroll
        for (int a2 = 0; a2 < 5; ++a2)
            #pragma unroll
            for (int d = 0; d < 8; ++d)
                r2v[a2][d] = ws[R2OFF + (size_t)a2 * R2SZ + (size_t)(n * 8 + d) * 1024 + pq];
        #pragma unroll
        for (int b2 = 0; b2 < 6; ++b2) {
            float s = 0.f;
            #pragma unroll
            for (int d = 0; d < 8; ++d) {
                const int cb = (d * 8 + so) * 69 + 16 + b2;
                #pragma unroll
                for (int a2 = 0; a2 < 5; ++a2) s += cs[cb + a2 * 6] * r2v[a2][d];
                s += cs[cb + 30] * s23[d * 32 + pql];
            }
            ws[T2OFF + (size_t)b2 * R2SZ + (size_t)(n * 8 + so) * 1024 + pq] = s;
        }
    } else {
        // ---- T1f for n = b-64; all red1 are 32-sums over red2 rows/cols ----
        const int n = b - 64;
        // phase A: r1[a1][d][p]
        {
            const int a1 = tt >> 6;          // 0..3
            const int dd = (tt >> 3) & 7;    // 0..7
            const int p0 = (tt & 7) * 4;
            const int src = (a1 == 0) ? 0 : ((a1 == 3) ? 4 : 3);
            const float* r2a = ws + R2OFF + (size_t)src * R2SZ + (size_t)(n * 8 + dd) * 1024;
            #pragma unroll
            for (int pp = 0; pp < 4; ++pp) {
                const int p = p0 + pp;
                float s = 0.f;
                if (a1 <= 1) { for (int q = 0; q < 32; ++q) s += r2a[p * 32 + q]; }
                else         { for (int q = 0; q < 32; ++q) s += r2a[q * 32 + p]; }
                r1[(a1 * 8 + dd) * 32 + p] = s;
            }
        }
        __syncthreads();
        // phase B: T1f[b1][n,so,p] = sum_{a1,d} cs[(d8+so)*69+a1*4+b1]*r1[a1][d][p]
        const int so = tt >> 5, p = tt & 31;
        #pragma unroll
        for (int b1 = 0; b1 < 4; ++b1) {
            float s = 0.f;
            #pragma unroll
            for (int a1 = 0; a1 < 4; ++a1)
                #pragma unroll
                for (int d = 0; d < 8; ++d)
                    s += cs[(d * 8 + so) * 69 + a1 * 4 + b1] * r1[(a1 * 8 + d) * 32 + p];
            ws[T1OFF + (size_t)b1 * R1SZ + (size_t)(n * 8 + so) * 32 + p] = s;
        }
    }
}

// ---------------- K5: U3[b] = mixed red3 + folded T2f/T1f/bias ----------------
__global__ __launch_bounds__(256) void k_mix3(const float* __restrict__ coefs,
                                              const float* __restrict__ bias,
                                              float* __restrict__ ws) {
    __shared__ float cs[4416];
    for (int idx = threadIdx.x; idx < 4416; idx += 256) cs[idx] = coefs[idx];
    __syncthreads();
    const int blk = blockIdx.x;           // 1024 = n(1) | sop(2) | cb(7)
    const int cb  = blk & 127;
    const int sop = (blk >> 7) & 3;
    const int n   = blk >> 9;
    const int c   = cb * 256 + threadIdx.x;
    const int p1 = c >> 10, p2 = (c >> 5) & 31, p3 = c & 31;
    float v[4][8];
    #pragma unroll
    for (int a = 0; a < 4; ++a)
        #pragma unroll
        for (int d = 0; d < 8; ++d)
            v[a][d] = ws[R3OFF + (size_t)a * R3SZ + (size_t)(n * 8 + d) * 32768 + c];
    const float* T2 = ws + T2OFF;
    const float* T1 = ws + T1OFF;
    #pragma unroll
    for (int b = 0; b < 4; ++b) {
        #pragma unroll
        for (int so2 = 0; so2 < 2; ++so2) {
            const int so = sop * 2 + so2;
            float s = 0.f;
            #pragma unroll
            for (int a = 0; a < 4; ++a)
                #pragma unroll
                for (int d = 0; d < 8; ++d)
                    s += cs[(d * 8 + so) * 69 + 52 + a * 4 + b] * v[a][d];
            const size_t nso = (size_t)(n * 8 + so);
            if (b == 0) {
                s += T2[0 * R2SZ + nso * 1024 + p1 * 32 + p2];
                s += T2[1 * R2SZ + nso * 1024 + p1 * 32 + p3];
                s += T2[3 * R2SZ + nso * 1024 + p2 * 32 + p3];
                s += T1[0 * R1SZ + nso * 32 + p1];
                s += T1[1 * R1SZ + nso * 32 + p2];
                s += T1[2 * R1SZ + nso * 32 + p3];
                s += bias[so];
            } else if (b == 1) {
                s += T2[2 * R2SZ + nso * 1024 + p1 * 32 + p3];
                s += T2[4 * R2SZ + nso * 1024 + p2 * 32 + p3];
                s += T1[3 * R1SZ + nso * 32 + p3];
            } else if (b == 2) {
                s += T2[5 * R2SZ + nso * 1024 + p2 * 32 + p3];
            }
            ws[U3OFF + (size_t)b * R3SZ + nso * 32768 + c] = s;
        }
    }
}

// ---------------- K6: final broadcast-add + s=4 channel mix ----------------
__global__ __launch_bounds__(256) void k_final(const float* __restrict__ x,
                                               const float* __restrict__ coefs,
                                               const float* __restrict__ ws,
                                               float* __restrict__ out) {
    __shared__ float c68[64];
    if (threadIdx.x < 64) c68[threadIdx.x] = coefs[threadIdx.x * 69 + 68];
    __syncthreads();
    const int b = blockIdx.x;           // (n*32+i)*32 + j
    const int j = b & 31;
    const int i = (b >> 5) & 31;
    const int n = b >> 10;
    const int t = threadIdx.x;
    const int k = t >> 3, lq = t & 7;

    float4 xv[8];
    const float* xb = x + ((size_t)n << 23) + ((size_t)i << 15) + j * 1024 + k * 32 + lq * 4;
    #pragma unroll
    for (int d = 0; d < 8; ++d) xv[d] = *(const float4*)(xb + ((size_t)d << 20));

    const float* U = ws + U3OFF;
    const size_t c012 = (size_t)i * 1024 + j * 32 + k;
    const size_t c013 = (size_t)i * 1024 + j * 32 + lq * 4;
    const size_t c023 = (size_t)i * 1024 + k * 32 + lq * 4;
    const size_t c123 = (size_t)j * 1024 + k * 32 + lq * 4;

    #pragma unroll
    for (int so = 0; so < 8; ++so) {
        const size_t nso = (size_t)(n * 8 + so) << 15;
        const float  u0 = U[0 * R3SZ + nso + c012];
        const float4 u1 = *(const float4*)(U + 1 * R3SZ + nso + c013);
        const float4 u2 = *(const float4*)(U + 2 * R3SZ + nso + c023);
        const float4 u3 = *(const float4*)(U + 3 * R3SZ + nso + c123);
        float4 acc;
        acc.x = u0 + u1.x + u2.x + u3.x;
        acc.y = u0 + u1.y + u2.y + u3.y;
        acc.z = u0 + u1.z + u2.z + u3.z;
        acc.w = u0 + u1.w + u2.w + u3.w;
        #pragma unroll
        for (int d = 0; d < 8; ++d) {
            const float w = c68[d * 8 + so];
            acc.x += w * xv[d].x; acc.y += w * xv[d].y;
            acc.z += w * xv[d].z; acc.w += w * xv[d].w;
        }
        *(float4*)(out + ((size_t)(n * 8 + so) << 20) + ((size_t)i << 15)
                   + j * 1024 + k * 32 + lq * 4) = acc;
    }
}

extern "C" void kernel_launch(void* const* d_in, const int* in_sizes, int n_in,
                              void* d_out, int out_size, void* d_ws, size_t ws_size,
                              hipStream_t stream) {
    const float* x     = (const float*)d_in[0];
    const float* coefs = (const float*)d_in[1];
    const float* bias  = (const float*)d_in[2];
    float* out = (float*)d_out;
    float* ws  = (float*)d_ws;

    hipLaunchKernelGGL(k_red3, dim3(1024), dim3(512), 0, stream, x, ws);
    hipLaunchKernelGGL(k_mixT, dim3(66),   dim3(256), 0, stream, coefs, ws);
    hipLaunchKernelGGL(k_mix3, dim3(1024), dim3(256), 0, stream, coefs, bias, ws);
    hipLaunchKernelGGL(k_final, dim3(2048), dim3(256), 0, stream, x, coefs, ws, out);
}